// Round 3
// baseline (204.732 us; speedup 1.0000x reference)
//
#include <hip/hip_runtime.h>

#define HH 64
#define WW 64

typedef _Float16 f16;
typedef f16 f16x8 __attribute__((ext_vector_type(8)));
typedef f16 f16x4 __attribute__((ext_vector_type(4)));
typedef float f32x4 __attribute__((ext_vector_type(4)));

// ws: ws[0..63] = fp32 logit bias; then f16 region (offsets in halves):
#define M1_H 0         // [c][r*4+s][lane][j] : 49152
#define BU_H 49152     // [c][r*4+s][lane][j] : 49152
#define BF_H 98304     // [g][r][lane][j]     : 12288
#define BC_H 110592    // [c2][s][lane][j]    : 4096
#define VT_H 114688    // [pixel][ch=n*8+slot]: 8388608  (slot: d=2*(slot&3)+(slot>>2))
#define PREP_N (64 + 114688)

__global__ __launch_bounds__(256) void prep_kernel(
    const float* __restrict__ attw, const float* __restrict__ ctw,
    const float* __restrict__ ctb, const float* __restrict__ few,
    const float* __restrict__ caw, float* __restrict__ ws) {
  int i = blockIdx.x * 256 + threadIdx.x;
  if (i >= PREP_N) return;
  f16* hb = (f16*)(ws + 64);
  if (i < 64) {
    int s = i >> 4, l15 = i & 15;
    int o = 2 * s + (l15 >> 3), n = l15 & 7;
    float acc = 0.f;
    for (int c = 0; c < 8; ++c)
      for (int d = 0; d < 8; ++d)
        acc += ctb[c * 64 + d * 8 + n] * attw[d * 512 + c * 64 + n * 8 + o];
    ws[i] = acc;
    return;
  }
  int z = i - 64;
  if (z < BU_H) {
    int j = z & 7, lane = (z >> 3) & 63, rest = z >> 9;
    int rs = rest % 12, c = rest / 12;
    int r = rs >> 2, s = rs & 3;
    int q = lane >> 4, l15 = lane & 15;
    int t = r * 4 + q;
    int o = 2 * s + (l15 >> 3), n = l15 & 7;
    float acc = 0.f;
    if (t < 9)
      for (int d = 0; d < 8; ++d)
        acc += ctw[(t * 8 + j) * 512 + c * 64 + d * 8 + n] *
               attw[d * 512 + c * 64 + n * 8 + o];
    hb[M1_H + z] = (f16)acc;
  } else if (z < BF_H) {
    int z2 = z - BU_H;
    int j = z2 & 7, lane = (z2 >> 3) & 63, rest = z2 >> 9;
    int rs = rest % 12, c = rest / 12;
    int r = rs >> 2, s = rs & 3;
    int q = lane >> 4, l15 = lane & 15;
    int t = r * 4 + q;
    int d = 2 * s + (l15 >> 3), n = l15 & 7;
    float v = (t < 9) ? ctw[(t * 8 + j) * 512 + c * 64 + d * 8 + n] : 0.f;
    hb[z] = (f16)v;
  } else if (z < BC_H) {
    int z2 = z - BF_H;
    int j = z2 & 7, lane = (z2 >> 3) & 63, rest = z2 >> 9;
    int r = rest % 3, g = rest / 3;
    int q = lane >> 4, l15 = lane & 15;
    int t = r * 4 + q;
    int d = 2 * (j & 3) + (j >> 2);
    float v = 0.f;
    if (t < 9 && ((l15 >> 3) == (g & 1)))
      v = few[(t * 8 + d) * 64 + g * 8 + (l15 & 7)];
    hb[z] = (f16)v;
  } else if (z < VT_H) {
    int z2 = z - BC_H;
    int j = z2 & 7, lane = (z2 >> 3) & 63, rest = z2 >> 9;
    int s = rest & 3, c2 = rest >> 2;
    int q = lane >> 4, l15 = lane & 15;
    int nk = c2 * 4 + q;
    int nc = 2 * s + (l15 >> 3);
    float v = (nk == nc) ? caw[j * 64 + nc * 8 + (l15 & 7)] : 0.f;
    hb[z] = (f16)v;
  }
}

// Stage 1: logits GEMM -> softmax -> u GEMM + fold -> vt.
// R3 = R2's forced distance-2 register pipeline (fully unrolled c-loops,
// sched_barrier(0) pins after each prefetch batch, static-c register fold)
// with R1's PROVEN barrier structure fully restored (no wave-private-LDS
// shortcuts): halo -> post-softmax -> post-pass2 -> pre-store.
__global__ __launch_bounds__(256, 2) void caps_stage1(
    const float* __restrict__ in, const float* __restrict__ ws,
    const float* __restrict__ ctb, f16* __restrict__ vt) {
  __shared__ f16 xt[181 * 72];    // 26.1 KB, hp=180 = zero row
  __shared__ f16 attb[128 * 72];  // 18.4 KB; reused as vtmp in epilogue
  int bid = blockIdx.x;
  int b = bid >> 5, t5 = bid & 31;
  int ty = t5 >> 3, tx = t5 & 7;
  int tid = threadIdx.x;

  // fill halo tile (fp32 -> f16, transpose to ch = c*8+dd)
#pragma unroll
  for (int k = 0; k < 6; ++k) {
    int i = tid + k * 256;
    if (i < 181 * 8) {
      int c = i & 7, hp = i >> 3;
      float xs[8] = {0.f, 0.f, 0.f, 0.f, 0.f, 0.f, 0.f, 0.f};
      if (hp < 180) {
        int hy = hp / 10, hx = hp - hy * 10;
        int gy = ty * 16 + hy - 1, gx = tx * 8 + hx - 1;
        if (gy >= 0 && gy < HH && gx >= 0 && gx < WW) {
          const float* src = in + (((b * HH + gy) * WW + gx) * 64 + c);
#pragma unroll
          for (int d = 0; d < 8; ++d) xs[d] = src[d * 8];
        }
      }
      f16x8 pk;
#pragma unroll
      for (int d = 0; d < 8; ++d) pk[d] = (f16)xs[d];
      *(f16x8*)&xt[hp * 72 + c * 8] = pk;
    }
  }

  int w = __builtin_amdgcn_readfirstlane(tid >> 6);
  int lane = tid & 63;
  int q = lane >> 4, l15 = lane & 15;
  int h = l15 >> 3, n = l15 & 7;

  int hpt[2][3];
#pragma unroll
  for (int i2 = 0; i2 < 2; ++i2) {
    int pyA = (2 * w + i2) * 2 + h;
    int pxA = l15 & 7;
#pragma unroll
    for (int r = 0; r < 3; ++r) {
      int t = r * 4 + q;
      int hp = 180;
      if (t < 9) {
        int ky = t / 3, kx = t - ky * 3;
        hp = (pyA + ky) * 10 + pxA + kx;
      }
      hpt[i2][r] = hp * 72;
    }
  }

  const f16x8* m1v = (const f16x8*)((const f16*)(ws + 64) + M1_H);
  const f16x8* buv = (const f16x8*)((const f16*)(ws + 64) + BU_H);
  const float* lb = ws;

  // L init + preload bm(c=0,1): issued before the fill barrier (free cover)
  f32x4 L[2][4];
#pragma unroll
  for (int s = 0; s < 4; ++s) {
    float v0 = lb[s * 16 + l15];
    L[0][s] = (f32x4){v0, v0, v0, v0};
    L[1][s] = (f32x4){v0, v0, v0, v0};
  }
  f16x8 bmb[2][12];
#pragma unroll
  for (int rs = 0; rs < 12; ++rs) bmb[0][rs] = m1v[rs * 64 + lane];
#pragma unroll
  for (int rs = 0; rs < 12; ++rs) bmb[1][rs] = m1v[(12 + rs) * 64 + lane];
  __builtin_amdgcn_sched_barrier(0);
  __syncthreads();

  // ---- pass 1: logits GEMM, distance-2 prefetch, fully unrolled ----
#pragma unroll
  for (int c = 0; c < 8; ++c) {
    f16x8 a0[3], a1[3];
#pragma unroll
    for (int r = 0; r < 3; ++r) {
      a0[r] = *(const f16x8*)&xt[hpt[0][r] + c * 8];
      a1[r] = *(const f16x8*)&xt[hpt[1][r] + c * 8];
    }
#pragma unroll
    for (int s = 0; s < 4; ++s)
#pragma unroll
      for (int r = 0; r < 3; ++r) {
        L[0][s] = __builtin_amdgcn_mfma_f32_16x16x32_f16(
            a0[r], bmb[c & 1][r * 4 + s], L[0][s], 0, 0, 0);
        L[1][s] = __builtin_amdgcn_mfma_f32_16x16x32_f16(
            a1[r], bmb[c & 1][r * 4 + s], L[1][s], 0, 0, 0);
      }
    if (c < 6) {
#pragma unroll
      for (int rs = 0; rs < 12; ++rs)
        bmb[c & 1][rs] = m1v[((c + 2) * 12 + rs) * 64 + lane];
      __builtin_amdgcn_sched_barrier(0);
    }
  }

  // ---- preload pass2 B(c=0,1) + biases: latency hides under softmax ----
  f16x8 bub[2][12];
#pragma unroll
  for (int rs = 0; rs < 12; ++rs) bub[0][rs] = buv[rs * 64 + lane];
#pragma unroll
  for (int rs = 0; rs < 12; ++rs) bub[1][rs] = buv[(12 + rs) * 64 + lane];
  float cbb[2][4];
#pragma unroll
  for (int s = 0; s < 4; ++s) {
    cbb[0][s] = ctb[s * 16 + l15];
    cbb[1][s] = ctb[64 + s * 16 + l15];
  }
  __builtin_amdgcn_sched_barrier(0);

  // ---- softmax over o (4 in-lane s-frags + lane^8), att -> LDS ----
#pragma unroll
  for (int i2 = 0; i2 < 2; ++i2) {
    int pbase = (2 * w + i2) * 16 + q * 4;
#pragma unroll
    for (int r = 0; r < 4; ++r) {
      float v0 = L[i2][0][r], v1 = L[i2][1][r], v2 = L[i2][2][r], v3 = L[i2][3][r];
      float pm = fmaxf(fmaxf(v0, v1), fmaxf(v2, v3));
      float m = fmaxf(pm, __shfl_xor(pm, 8));
      float e0 = __expf(v0 - m), e1 = __expf(v1 - m);
      float e2 = __expf(v2 - m), e3 = __expf(v3 - m);
      float ps = e0 + e1 + e2 + e3;
      float inv = 1.f / (ps + __shfl_xor(ps, 8));
      int ab = (pbase + r) * 72 + n * 8 + h;  // o = 2s + h
      attb[ab + 0] = (f16)(e0 * inv);
      attb[ab + 2] = (f16)(e1 * inv);
      attb[ab + 4] = (f16)(e2 * inv);
      attb[ab + 6] = (f16)(e3 * inv);
    }
  }
  __syncthreads();

  // att rows -> registers, one b128 per (i2,r); static extracts in the fold
  f16x8 atv[2][4];
#pragma unroll
  for (int i2 = 0; i2 < 2; ++i2)
#pragma unroll
    for (int r = 0; r < 4; ++r)
      atv[i2][r] =
          *(const f16x8*)&attb[((2 * w + i2) * 16 + q * 4 + r) * 72 + n * 8];

  // ---- pass 2: u GEMM + fold, distance-2 prefetch, fully unrolled ----
  f32x4 V[2][4];
#pragma unroll
  for (int s = 0; s < 4; ++s) {
    V[0][s] = (f32x4){0.f, 0.f, 0.f, 0.f};
    V[1][s] = (f32x4){0.f, 0.f, 0.f, 0.f};
  }
#pragma unroll
  for (int c = 0; c < 8; ++c) {
#pragma unroll
    for (int i2 = 0; i2 < 2; ++i2) {
      f16x8 a[3];
#pragma unroll
      for (int r = 0; r < 3; ++r)
        a[r] = *(const f16x8*)&xt[hpt[i2][r] + c * 8];
      f32x4 U[4];
#pragma unroll
      for (int s = 0; s < 4; ++s) {
        float bv = cbb[c & 1][s];
        U[s] = (f32x4){bv, bv, bv, bv};
      }
#pragma unroll
      for (int s = 0; s < 4; ++s)
#pragma unroll
        for (int r = 0; r < 3; ++r)
          U[s] = __builtin_amdgcn_mfma_f32_16x16x32_f16(
              a[r], bub[c & 1][r * 4 + s], U[s], 0, 0, 0);
#pragma unroll
      for (int r = 0; r < 4; ++r) {
        float af = (float)atv[i2][r][c];  // static c: plain sub-reg extract
#pragma unroll
        for (int s = 0; s < 4; ++s) V[i2][s][r] += U[s][r] * af;
      }
    }
    if (c < 6) {
#pragma unroll
      for (int rs = 0; rs < 12; ++rs)
        bub[c & 1][rs] = buv[((c + 2) * 12 + rs) * 64 + lane];
#pragma unroll
      for (int s = 0; s < 4; ++s)
        cbb[c & 1][s] = ctb[(c + 2) * 64 + s * 16 + l15];
      __builtin_amdgcn_sched_barrier(0);
    }
  }

  // ---- epilogue: transpose V through attb (as vtmp), coalesced stores ----
  __syncthreads();  // all waves done reading attb (atv) before overwrite
  f16* vtmp = attb;
#pragma unroll
  for (int i2 = 0; i2 < 2; ++i2)
#pragma unroll
    for (int r = 0; r < 4; ++r) {
      int p = (2 * w + i2) * 16 + q * 4 + r;
      f16x4 st;
#pragma unroll
      for (int s = 0; s < 4; ++s) st[s] = (f16)V[i2][s][r];  // slot=h*4+s, d=2s+h
      *(f16x4*)&vtmp[p * 72 + n * 8 + h * 4] = st;
    }
  __syncthreads();
  for (int idx = tid; idx < 1024; idx += 256) {
    int p = idx >> 3, q2 = idx & 7;
    float4 val = *(float4*)&vtmp[p * 72 + q2 * 8];
    int gy = ty * 16 + (p >> 3), gx = tx * 8 + (p & 7);
    ((float4*)(vt + ((b * HH + gy) * WW + gx) * 64))[q2] = val;
  }
}

// Stage 2: FeaExt GEMM (block-diag) + ReLU + CapsAct GEMM -> out
// R3: bcf preload under the fill barrier; all R1 barriers kept.
__global__ __launch_bounds__(256, 2) void caps_stage2(
    const f16* __restrict__ vt, const float* __restrict__ ws,
    const float* __restrict__ fb, const float* __restrict__ cab,
    float* __restrict__ out) {
  __shared__ float smemf[8704];  // 34.8 KB: vtile / h1t / outbuf aliased
  f16* vtile = (f16*)smemf;
  int bid = blockIdx.x;
  int b = bid >> 5, t5 = bid & 31;
  int ty = t5 >> 3, tx = t5 & 7;
  int tid = threadIdx.x;

#pragma unroll
  for (int k = 0; k < 6; ++k) {
    int i = tid + k * 256;
    if (i < 181 * 8) {
      int q2 = i & 7, hp = i >> 3;
      float4 val = make_float4(0.f, 0.f, 0.f, 0.f);
      if (hp < 180) {
        int hy = hp / 10, hx = hp - hy * 10;
        int gy = ty * 16 + hy - 1, gx = tx * 8 + hx - 1;
        if (gy >= 0 && gy < HH && gx >= 0 && gx < WW)
          val = ((const float4*)(vt + ((b * HH + gy) * WW + gx) * 64))[q2];
      }
      *(float4*)&vtile[hp * 72 + q2 * 8] = val;
    }
  }

  int w = __builtin_amdgcn_readfirstlane(tid >> 6);
  int lane = tid & 63;
  int q = lane >> 4, l15 = lane & 15;
  int h = l15 >> 3, j7 = l15 & 7;

  int hpt[2][3];
#pragma unroll
  for (int i2 = 0; i2 < 2; ++i2) {
    int pyA = (2 * w + i2) * 2 + h;
#pragma unroll
    for (int r = 0; r < 3; ++r) {
      int t = r * 4 + q;
      int hp = 180;
      if (t < 9) {
        int ky = t / 3, kx = t - ky * 3;
        hp = (pyA + ky) * 10 + j7 + kx;
      }
      hpt[i2][r] = hp * 72;
    }
  }

  const f16x8* bfv = (const f16x8*)((const f16*)(ws + 64) + BF_H);
  const f16x8* bcv = (const f16x8*)((const f16*)(ws + 64) + BC_H);

  // preload CapsAct B-frags: latency hides under fill + FeaExt
  f16x8 bcf[8];
#pragma unroll
  for (int k = 0; k < 8; ++k) bcf[k] = bcv[k * 64 + lane];
  __builtin_amdgcn_sched_barrier(0);
  __syncthreads();

  // FeaExt: col (n=2s+h, j=j7); input chunk g feeds only s = g>>1
  f32x4 L[2][4];
#pragma unroll
  for (int s = 0; s < 4; ++s) {
    float bvv = fb[(2 * s + h) * 8 + j7];
    L[0][s] = (f32x4){bvv, bvv, bvv, bvv};
    L[1][s] = (f32x4){bvv, bvv, bvv, bvv};
  }
#pragma unroll
  for (int g = 0; g < 8; ++g) {
    int sg = g >> 1;
#pragma unroll
    for (int r = 0; r < 3; ++r) {
      f16x8 bf = bfv[(g * 3 + r) * 64 + lane];
#pragma unroll
      for (int i2 = 0; i2 < 2; ++i2) {
        f16x8 a = *(const f16x8*)&vtile[hpt[i2][r] + g * 8];
        L[i2][sg] = __builtin_amdgcn_mfma_f32_16x16x32_f16(a, bf, L[i2][sg], 0, 0, 0);
      }
    }
  }
#pragma unroll
  for (int i2 = 0; i2 < 2; ++i2)
#pragma unroll
    for (int s = 0; s < 4; ++s)
#pragma unroll
      for (int r = 0; r < 4; ++r) L[i2][s][r] = fmaxf(L[i2][s][r], 0.f);

  __syncthreads();  // vtile reads done; alias h1t
  f16* h1t = (f16*)smemf;  // [128][72], ch2 = n*8 + j1
#pragma unroll
  for (int i2 = 0; i2 < 2; ++i2)
#pragma unroll
    for (int s = 0; s < 4; ++s)
#pragma unroll
      for (int r = 0; r < 4; ++r)
        h1t[((2 * w + i2) * 16 + q * 4 + r) * 72 + (2 * s + h) * 8 + j7] =
            (f16)L[i2][s][r];
  __syncthreads();

  // CapsAct: K=64 over (j1, n) block-diag
  f32x4 H[2][4];
#pragma unroll
  for (int s = 0; s < 4; ++s) {
    float bvv = cab[(2 * s + h) * 8 + j7];
    H[0][s] = (f32x4){bvv, bvv, bvv, bvv};
    H[1][s] = (f32x4){bvv, bvv, bvv, bvv};
  }
#pragma unroll
  for (int c2 = 0; c2 < 2; ++c2) {
    f16x8 a2[2];
#pragma unroll
    for (int i2 = 0; i2 < 2; ++i2)
      a2[i2] = *(const f16x8*)&h1t[((2 * w + i2) * 16 + l15) * 72 + c2 * 32 + q * 8];
#pragma unroll
    for (int s = 0; s < 4; ++s) {
#pragma unroll
      for (int i2 = 0; i2 < 2; ++i2)
        H[i2][s] = __builtin_amdgcn_mfma_f32_16x16x32_f16(
            a2[i2], bcf[c2 * 4 + s], H[i2][s], 0, 0, 0);
    }
  }

  __syncthreads();  // h1t reads done; alias outbuf
  float* outbuf = smemf;  // [128][68], ch = j2*8 + n
#pragma unroll
  for (int i2 = 0; i2 < 2; ++i2)
#pragma unroll
    for (int s = 0; s < 4; ++s)
#pragma unroll
      for (int r = 0; r < 4; ++r)
        outbuf[((2 * w + i2) * 16 + q * 4 + r) * 68 + j7 * 8 + 2 * s + h] =
            H[i2][s][r];
  __syncthreads();

  for (int idx = tid; idx < 2048; idx += 256) {
    int p = idx >> 4, q4 = idx & 15;
    float4 val = *(float4*)&outbuf[p * 68 + q4 * 4];
    int gy = ty * 16 + (p >> 3), gx = tx * 8 + (p & 7);
    *(float4*)(out + ((b * HH + gy) * WW + gx) * 64 + q4 * 4) = val;
  }
}

extern "C" void kernel_launch(void* const* d_in, const int* in_sizes, int n_in,
                              void* d_out, int out_size, void* d_ws, size_t ws_size,
                              hipStream_t stream) {
  const float* inputs = (const float*)d_in[0];
  const float* attw   = (const float*)d_in[1];
  const float* ctw    = (const float*)d_in[2];
  const float* ctb    = (const float*)d_in[3];
  const float* few    = (const float*)d_in[4];
  const float* fb     = (const float*)d_in[5];
  const float* caw    = (const float*)d_in[6];
  const float* cab    = (const float*)d_in[7];
  float* out = (float*)d_out;
  float* ws  = (float*)d_ws;
  f16* vt = (f16*)(ws + 64) + VT_H;

  prep_kernel<<<(PREP_N + 255) / 256, 256, 0, stream>>>(attw, ctw, ctb, few, caw, ws);
  caps_stage1<<<32 * 32, 256, 0, stream>>>(inputs, ws, ctb, vt);
  caps_stage2<<<32 * 32, 256, 0, stream>>>(vt, ws, fb, cab, out);
}

// Round 4
// 191.601 us; speedup vs baseline: 1.0685x; 1.0685x over previous
//
#include <hip/hip_runtime.h>

#define HH 64
#define WW 64

typedef _Float16 f16;
typedef f16 f16x8 __attribute__((ext_vector_type(8)));
typedef f16 f16x4 __attribute__((ext_vector_type(4)));
typedef float f32x4 __attribute__((ext_vector_type(4)));

// ws: ws[0..63] = fp32 logit bias; then f16 region (offsets in halves):
#define M1_H 0         // [c][r*4+s][lane][j] : 49152
#define BU_H 49152     // [c][r*4+s][lane][j] : 49152
#define BF_H 98304     // [g][r][lane][j]     : 12288
#define BC_H 110592    // [c2][s][lane][j]    : 4096
#define VT_H 114688    // [pixel][ch=n*8+slot]: 8388608  (slot: d=2*(slot&3)+(slot>>2))
#define PREP_N (64 + 114688)

__global__ __launch_bounds__(256) void prep_kernel(
    const float* __restrict__ attw, const float* __restrict__ ctw,
    const float* __restrict__ ctb, const float* __restrict__ few,
    const float* __restrict__ caw, float* __restrict__ ws) {
  int i = blockIdx.x * 256 + threadIdx.x;
  if (i >= PREP_N) return;
  f16* hb = (f16*)(ws + 64);
  if (i < 64) {
    int s = i >> 4, l15 = i & 15;
    int o = 2 * s + (l15 >> 3), n = l15 & 7;
    float acc = 0.f;
    for (int c = 0; c < 8; ++c)
      for (int d = 0; d < 8; ++d)
        acc += ctb[c * 64 + d * 8 + n] * attw[d * 512 + c * 64 + n * 8 + o];
    ws[i] = acc;
    return;
  }
  int z = i - 64;
  if (z < BU_H) {
    int j = z & 7, lane = (z >> 3) & 63, rest = z >> 9;
    int rs = rest % 12, c = rest / 12;
    int r = rs >> 2, s = rs & 3;
    int q = lane >> 4, l15 = lane & 15;
    int t = r * 4 + q;
    int o = 2 * s + (l15 >> 3), n = l15 & 7;
    float acc = 0.f;
    if (t < 9)
      for (int d = 0; d < 8; ++d)
        acc += ctw[(t * 8 + j) * 512 + c * 64 + d * 8 + n] *
               attw[d * 512 + c * 64 + n * 8 + o];
    hb[M1_H + z] = (f16)acc;
  } else if (z < BF_H) {
    int z2 = z - BU_H;
    int j = z2 & 7, lane = (z2 >> 3) & 63, rest = z2 >> 9;
    int rs = rest % 12, c = rest / 12;
    int r = rs >> 2, s = rs & 3;
    int q = lane >> 4, l15 = lane & 15;
    int t = r * 4 + q;
    int d = 2 * s + (l15 >> 3), n = l15 & 7;
    float v = (t < 9) ? ctw[(t * 8 + j) * 512 + c * 64 + d * 8 + n] : 0.f;
    hb[z] = (f16)v;
  } else if (z < BC_H) {
    int z2 = z - BF_H;
    int j = z2 & 7, lane = (z2 >> 3) & 63, rest = z2 >> 9;
    int r = rest % 3, g = rest / 3;
    int q = lane >> 4, l15 = lane & 15;
    int t = r * 4 + q;
    int d = 2 * (j & 3) + (j >> 2);
    float v = 0.f;
    if (t < 9 && ((l15 >> 3) == (g & 1)))
      v = few[(t * 8 + d) * 64 + g * 8 + (l15 & 7)];
    hb[z] = (f16)v;
  } else if (z < VT_H) {
    int z2 = z - BC_H;
    int j = z2 & 7, lane = (z2 >> 3) & 63, rest = z2 >> 9;
    int s = rest & 3, c2 = rest >> 2;
    int q = lane >> 4, l15 = lane & 15;
    int nk = c2 * 4 + q;
    int nc = 2 * s + (l15 >> 3);
    float v = (nk == nc) ? caw[j * 64 + nc * 8 + (l15 & 7)] : 0.f;
    hb[z] = (f16)v;
  }
}

// Stage 1 (R1-proven structure): logits GEMM -> softmax via LDS attb ->
// u GEMM + attention fold -> vt. R4: only change vs R1 is
// __launch_bounds__(256,3) -> 3 blocks/CU resident (LDS 3x44.5KB fits 160KB,
// VGPR cap ~170 > 112 so no spill) for more cross-wave latency hiding.
__global__ __launch_bounds__(256, 3) void caps_stage1(
    const float* __restrict__ in, const float* __restrict__ ws,
    const float* __restrict__ ctb, f16* __restrict__ vt) {
  __shared__ f16 xt[181 * 72];    // 26.1 KB, hp=180 = zero row
  __shared__ f16 attb[128 * 72];  // 18.4 KB; reused as vtmp in epilogue
  int bid = blockIdx.x;
  int b = bid >> 5, t5 = bid & 31;
  int ty = t5 >> 3, tx = t5 & 7;
  int tid = threadIdx.x;

  // fill halo tile (fp32 -> f16, transpose to ch = c*8+dd); fixed 6 trips so
  // all iterations' loads can be in flight concurrently
#pragma unroll
  for (int k = 0; k < 6; ++k) {
    int i = tid + k * 256;
    if (i < 181 * 8) {
      int c = i & 7, hp = i >> 3;
      float xs[8] = {0.f, 0.f, 0.f, 0.f, 0.f, 0.f, 0.f, 0.f};
      if (hp < 180) {
        int hy = hp / 10, hx = hp - hy * 10;
        int gy = ty * 16 + hy - 1, gx = tx * 8 + hx - 1;
        if (gy >= 0 && gy < HH && gx >= 0 && gx < WW) {
          const float* src = in + (((b * HH + gy) * WW + gx) * 64 + c);
#pragma unroll
          for (int d = 0; d < 8; ++d) xs[d] = src[d * 8];
        }
      }
      f16x8 pk;
#pragma unroll
      for (int d = 0; d < 8; ++d) pk[d] = (f16)xs[d];
      *(f16x8*)&xt[hp * 72 + c * 8] = pk;
    }
  }
  __syncthreads();

  int w = __builtin_amdgcn_readfirstlane(tid >> 6);
  int lane = tid & 63;
  int q = lane >> 4, l15 = lane & 15;
  int h = l15 >> 3, n = l15 & 7;

  int hpt[2][3];
#pragma unroll
  for (int i2 = 0; i2 < 2; ++i2) {
    int pyA = (2 * w + i2) * 2 + h;
    int pxA = l15 & 7;
#pragma unroll
    for (int r = 0; r < 3; ++r) {
      int t = r * 4 + q;
      int hp = 180;
      if (t < 9) {
        int ky = t / 3, kx = t - ky * 3;
        hp = (pyA + ky) * 10 + pxA + kx;
      }
      hpt[i2][r] = hp * 72;
    }
  }

  const f16x8* m1v = (const f16x8*)((const f16*)(ws + 64) + M1_H);
  const f16x8* buv = (const f16x8*)((const f16*)(ws + 64) + BU_H);
  const float* lb = ws;

  // ---- pass 1: attention logits via MFMA, double-buffered B prefetch ----
  f32x4 L[2][4];
#pragma unroll
  for (int s = 0; s < 4; ++s) {
    float v0 = lb[s * 16 + l15];
    L[0][s] = (f32x4){v0, v0, v0, v0};
    L[1][s] = (f32x4){v0, v0, v0, v0};
  }

  f16x8 bmA[12], bmB[12];
#pragma unroll
  for (int rs = 0; rs < 12; ++rs) bmA[rs] = m1v[rs * 64 + lane];

  auto p1step = [&](int c, const f16x8(&bm)[12]) {
    f16x8 a[2][3];
#pragma unroll
    for (int i2 = 0; i2 < 2; ++i2)
#pragma unroll
      for (int r = 0; r < 3; ++r)
        a[i2][r] = *(const f16x8*)&xt[hpt[i2][r] + c * 8];
#pragma unroll
    for (int i2 = 0; i2 < 2; ++i2)
#pragma unroll
      for (int s = 0; s < 4; ++s)
#pragma unroll
        for (int r = 0; r < 3; ++r)
          L[i2][s] = __builtin_amdgcn_mfma_f32_16x16x32_f16(
              a[i2][r], bm[r * 4 + s], L[i2][s], 0, 0, 0);
  };

#pragma unroll 1
  for (int cc = 0; cc < 4; ++cc) {
    int c0 = 2 * cc;
#pragma unroll
    for (int rs = 0; rs < 12; ++rs)
      bmB[rs] = m1v[((c0 + 1) * 12 + rs) * 64 + lane];
    p1step(c0, bmA);
    if (cc < 3) {
#pragma unroll
      for (int rs = 0; rs < 12; ++rs)
        bmA[rs] = m1v[((c0 + 2) * 12 + rs) * 64 + lane];
    }
    p1step(c0 + 1, bmB);
  }

  // ---- cross-pass prefetch: BU(c=0) + bias(c=0) hide under softmax ----
  f16x8 buA[12], buB[12];
#pragma unroll
  for (int rs = 0; rs < 12; ++rs) buA[rs] = buv[rs * 64 + lane];
  float cbA[4], cbB[4];
#pragma unroll
  for (int s = 0; s < 4; ++s) cbA[s] = ctb[s * 16 + l15];

  // ---- softmax over o (4 in-lane s-frags + lane^8), att -> LDS ----
#pragma unroll
  for (int i2 = 0; i2 < 2; ++i2) {
    int pbase = (2 * w + i2) * 16 + q * 4;
#pragma unroll
    for (int r = 0; r < 4; ++r) {
      float v0 = L[i2][0][r], v1 = L[i2][1][r], v2 = L[i2][2][r], v3 = L[i2][3][r];
      float pm = fmaxf(fmaxf(v0, v1), fmaxf(v2, v3));
      float m = fmaxf(pm, __shfl_xor(pm, 8));
      float e0 = __expf(v0 - m), e1 = __expf(v1 - m);
      float e2 = __expf(v2 - m), e3 = __expf(v3 - m);
      float ps = e0 + e1 + e2 + e3;
      float inv = 1.f / (ps + __shfl_xor(ps, 8));
      int ab = (pbase + r) * 72 + n * 8 + h;  // o = 2s + h
      attb[ab + 0] = (f16)(e0 * inv);
      attb[ab + 2] = (f16)(e1 * inv);
      attb[ab + 4] = (f16)(e2 * inv);
      attb[ab + 6] = (f16)(e3 * inv);
    }
  }
  __syncthreads();

  // att row base offsets for the fold (static-indexed)
  int ab[2][4];
#pragma unroll
  for (int i2 = 0; i2 < 2; ++i2)
#pragma unroll
    for (int r = 0; r < 4; ++r)
      ab[i2][r] = ((2 * w + i2) * 16 + q * 4 + r) * 72 + n * 8;

  // ---- pass 2: u GEMM per c + attention fold (att via scalar LDS reads) ----
  f32x4 V[2][4];
#pragma unroll
  for (int s = 0; s < 4; ++s) {
    V[0][s] = (f32x4){0.f, 0.f, 0.f, 0.f};
    V[1][s] = (f32x4){0.f, 0.f, 0.f, 0.f};
  }

  auto p2step = [&](int c, const f16x8(&bu)[12], const float(&cb)[4]) {
#pragma unroll
    for (int i2 = 0; i2 < 2; ++i2) {
      f16x8 a[3];
#pragma unroll
      for (int r = 0; r < 3; ++r)
        a[r] = *(const f16x8*)&xt[hpt[i2][r] + c * 8];
      f32x4 U[4];
#pragma unroll
      for (int s = 0; s < 4; ++s) U[s] = (f32x4){cb[s], cb[s], cb[s], cb[s]};
#pragma unroll
      for (int s = 0; s < 4; ++s)
#pragma unroll
        for (int r = 0; r < 3; ++r)
          U[s] = __builtin_amdgcn_mfma_f32_16x16x32_f16(
              a[r], bu[r * 4 + s], U[s], 0, 0, 0);
#pragma unroll
      for (int r = 0; r < 4; ++r) {
        float af = (float)attb[ab[i2][r] + c];
#pragma unroll
        for (int s = 0; s < 4; ++s) V[i2][s][r] += U[s][r] * af;
      }
    }
  };

#pragma unroll 1
  for (int cc = 0; cc < 4; ++cc) {
    int c0 = 2 * cc;
#pragma unroll
    for (int rs = 0; rs < 12; ++rs)
      buB[rs] = buv[((c0 + 1) * 12 + rs) * 64 + lane];
#pragma unroll
    for (int s = 0; s < 4; ++s) cbB[s] = ctb[(c0 + 1) * 64 + s * 16 + l15];
    p2step(c0, buA, cbA);
    if (cc < 3) {
#pragma unroll
      for (int rs = 0; rs < 12; ++rs)
        buA[rs] = buv[((c0 + 2) * 12 + rs) * 64 + lane];
#pragma unroll
      for (int s = 0; s < 4; ++s) cbA[s] = ctb[(c0 + 2) * 64 + s * 16 + l15];
    }
    p2step(c0 + 1, buB, cbB);
  }

  // ---- epilogue: transpose V through attb, coalesced b128 stores ----
  __syncthreads();
  f16* vtmp = attb;
#pragma unroll
  for (int i2 = 0; i2 < 2; ++i2)
#pragma unroll
    for (int r = 0; r < 4; ++r) {
      int p = (2 * w + i2) * 16 + q * 4 + r;
      f16x4 st;
#pragma unroll
      for (int s = 0; s < 4; ++s) st[s] = (f16)V[i2][s][r];  // slot=h*4+s, d=2s+h
      *(f16x4*)&vtmp[p * 72 + n * 8 + h * 4] = st;
    }
  __syncthreads();
  for (int idx = tid; idx < 1024; idx += 256) {
    int p = idx >> 3, q2 = idx & 7;
    float4 val = *(float4*)&vtmp[p * 72 + q2 * 8];
    int gy = ty * 16 + (p >> 3), gx = tx * 8 + (p & 7);
    ((float4*)(vt + ((b * HH + gy) * WW + gx) * 64))[q2] = val;
  }
}

// Stage 2: FeaExt GEMM (block-diag, 1 s-frag per chunk) + ReLU + CapsAct GEMM -> out
// R4: only change vs R1 is __launch_bounds__(256,3).
__global__ __launch_bounds__(256, 3) void caps_stage2(
    const f16* __restrict__ vt, const float* __restrict__ ws,
    const float* __restrict__ fb, const float* __restrict__ cab,
    float* __restrict__ out) {
  __shared__ float smemf[8704];  // 34.8 KB: vtile(26064B) / h1t(18432B) / outbuf aliased
  f16* vtile = (f16*)smemf;
  int bid = blockIdx.x;
  int b = bid >> 5, t5 = bid & 31;
  int ty = t5 >> 3, tx = t5 & 7;
  int tid = threadIdx.x;

  for (int i = tid; i < 181 * 8; i += 256) {
    int q2 = i & 7, hp = i >> 3;
    float4 val = make_float4(0.f, 0.f, 0.f, 0.f);
    if (hp < 180) {
      int hy = hp / 10, hx = hp - hy * 10;
      int gy = ty * 16 + hy - 1, gx = tx * 8 + hx - 1;
      if (gy >= 0 && gy < HH && gx >= 0 && gx < WW)
        val = ((const float4*)(vt + ((b * HH + gy) * WW + gx) * 64))[q2];
    }
    *(float4*)&vtile[hp * 72 + q2 * 8] = val;
  }
  __syncthreads();

  int w = __builtin_amdgcn_readfirstlane(tid >> 6);
  int lane = tid & 63;
  int q = lane >> 4, l15 = lane & 15;
  int h = l15 >> 3, j7 = l15 & 7;

  int hpt[2][3];
#pragma unroll
  for (int i2 = 0; i2 < 2; ++i2) {
    int pyA = (2 * w + i2) * 2 + h;
#pragma unroll
    for (int r = 0; r < 3; ++r) {
      int t = r * 4 + q;
      int hp = 180;
      if (t < 9) {
        int ky = t / 3, kx = t - ky * 3;
        hp = (pyA + ky) * 10 + j7 + kx;
      }
      hpt[i2][r] = hp * 72;
    }
  }

  const f16x8* bfv = (const f16x8*)((const f16*)(ws + 64) + BF_H);
  const f16x8* bcv = (const f16x8*)((const f16*)(ws + 64) + BC_H);

  // FeaExt: col (n=2s+h, j=j7); input chunk g feeds only s = g>>1
  f32x4 L[2][4];
#pragma unroll
  for (int s = 0; s < 4; ++s) {
    float bvv = fb[(2 * s + h) * 8 + j7];
    L[0][s] = (f32x4){bvv, bvv, bvv, bvv};
    L[1][s] = (f32x4){bvv, bvv, bvv, bvv};
  }
#pragma unroll
  for (int g = 0; g < 8; ++g) {
    int sg = g >> 1;
#pragma unroll
    for (int r = 0; r < 3; ++r) {
      f16x8 bf = bfv[(g * 3 + r) * 64 + lane];
#pragma unroll
      for (int i2 = 0; i2 < 2; ++i2) {
        f16x8 a = *(const f16x8*)&vtile[hpt[i2][r] + g * 8];
        L[i2][sg] = __builtin_amdgcn_mfma_f32_16x16x32_f16(a, bf, L[i2][sg], 0, 0, 0);
      }
    }
  }
#pragma unroll
  for (int i2 = 0; i2 < 2; ++i2)
#pragma unroll
    for (int s = 0; s < 4; ++s)
#pragma unroll
      for (int r = 0; r < 4; ++r) L[i2][s][r] = fmaxf(L[i2][s][r], 0.f);

  __syncthreads();  // vtile reads done; alias h1t
  f16* h1t = (f16*)smemf;  // [128][72], ch2 = n*8 + j1
#pragma unroll
  for (int i2 = 0; i2 < 2; ++i2)
#pragma unroll
    for (int s = 0; s < 4; ++s)
#pragma unroll
      for (int r = 0; r < 4; ++r)
        h1t[((2 * w + i2) * 16 + q * 4 + r) * 72 + (2 * s + h) * 8 + j7] =
            (f16)L[i2][s][r];
  __syncthreads();

  // CapsAct: K=64 over (j1, n) block-diag
  f32x4 H[2][4];
#pragma unroll
  for (int s = 0; s < 4; ++s) {
    float bvv = cab[(2 * s + h) * 8 + j7];
    H[0][s] = (f32x4){bvv, bvv, bvv, bvv};
    H[1][s] = (f32x4){bvv, bvv, bvv, bvv};
  }
#pragma unroll
  for (int c2 = 0; c2 < 2; ++c2) {
    f16x8 a2[2];
#pragma unroll
    for (int i2 = 0; i2 < 2; ++i2)
      a2[i2] = *(const f16x8*)&h1t[((2 * w + i2) * 16 + l15) * 72 + c2 * 32 + q * 8];
#pragma unroll
    for (int s = 0; s < 4; ++s) {
      f16x8 bc = bcv[(c2 * 4 + s) * 64 + lane];
#pragma unroll
      for (int i2 = 0; i2 < 2; ++i2)
        H[i2][s] = __builtin_amdgcn_mfma_f32_16x16x32_f16(a2[i2], bc, H[i2][s], 0, 0, 0);
    }
  }

  __syncthreads();  // h1t reads done; alias outbuf
  float* outbuf = smemf;  // [128][68], ch = j2*8 + n
#pragma unroll
  for (int i2 = 0; i2 < 2; ++i2)
#pragma unroll
    for (int s = 0; s < 4; ++s)
#pragma unroll
      for (int r = 0; r < 4; ++r)
        outbuf[((2 * w + i2) * 16 + q * 4 + r) * 68 + j7 * 8 + 2 * s + h] =
            H[i2][s][r];
  __syncthreads();

  for (int idx = tid; idx < 2048; idx += 256) {
    int p = idx >> 4, q4 = idx & 15;
    float4 val = *(float4*)&outbuf[p * 68 + q4 * 4];
    int gy = ty * 16 + (p >> 3), gx = tx * 8 + (p & 7);
    *(float4*)(out + ((b * HH + gy) * WW + gx) * 64 + q4 * 4) = val;
  }
}

extern "C" void kernel_launch(void* const* d_in, const int* in_sizes, int n_in,
                              void* d_out, int out_size, void* d_ws, size_t ws_size,
                              hipStream_t stream) {
  const float* inputs = (const float*)d_in[0];
  const float* attw   = (const float*)d_in[1];
  const float* ctw    = (const float*)d_in[2];
  const float* ctb    = (const float*)d_in[3];
  const float* few    = (const float*)d_in[4];
  const float* fb     = (const float*)d_in[5];
  const float* caw    = (const float*)d_in[6];
  const float* cab    = (const float*)d_in[7];
  float* out = (float*)d_out;
  float* ws  = (float*)d_ws;
  f16* vt = (f16*)(ws + 64) + VT_H;

  prep_kernel<<<(PREP_N + 255) / 256, 256, 0, stream>>>(attw, ctw, ctb, few, caw, ws);
  caps_stage1<<<32 * 32, 256, 0, stream>>>(inputs, ws, ctb, vt);
  caps_stage2<<<32 * 32, 256, 0, stream>>>(vt, ws, fb, cab, out);
}

// Round 5
// 140.975 us; speedup vs baseline: 1.4523x; 1.3591x over previous
//
#include <hip/hip_runtime.h>

#define HH 64
#define WW 64

typedef _Float16 f16;
typedef f16 f16x8 __attribute__((ext_vector_type(8)));
typedef f16 f16x4 __attribute__((ext_vector_type(4)));
typedef float f32x4 __attribute__((ext_vector_type(4)));

typedef __attribute__((address_space(3))) void lds_void;
typedef __attribute__((address_space(1))) const void gbl_void;

// ws: ws[0..63] = fp32 logit bias; then f16 region (offsets in halves):
#define M1_H 0         // [c][r*4+s][lane][j] : 49152
#define BU_H 49152     // [c][r*4+s][lane][j] : 49152
#define BF_H 98304     // [g][r][lane][j]     : 12288
#define BC_H 110592    // [c2][s][lane][j]    : 4096
#define VT_H 114688    // [pixel][ch=n*8+slot]: 8388608  (slot: d=2*(slot&3)+(slot>>2))
#define PREP_N (64 + 114688)

__global__ __launch_bounds__(256) void prep_kernel(
    const float* __restrict__ attw, const float* __restrict__ ctw,
    const float* __restrict__ ctb, const float* __restrict__ few,
    const float* __restrict__ caw, float* __restrict__ ws) {
  int i = blockIdx.x * 256 + threadIdx.x;
  if (i >= PREP_N) return;
  f16* hb = (f16*)(ws + 64);
  if (i < 64) {
    int s = i >> 4, l15 = i & 15;
    int o = 2 * s + (l15 >> 3), n = l15 & 7;
    float acc = 0.f;
    for (int c = 0; c < 8; ++c)
      for (int d = 0; d < 8; ++d)
        acc += ctb[c * 64 + d * 8 + n] * attw[d * 512 + c * 64 + n * 8 + o];
    ws[i] = acc;
    return;
  }
  int z = i - 64;
  if (z < BU_H) {
    int j = z & 7, lane = (z >> 3) & 63, rest = z >> 9;
    int rs = rest % 12, c = rest / 12;
    int r = rs >> 2, s = rs & 3;
    int q = lane >> 4, l15 = lane & 15;
    int t = r * 4 + q;
    int o = 2 * s + (l15 >> 3), n = l15 & 7;
    float acc = 0.f;
    if (t < 9)
      for (int d = 0; d < 8; ++d)
        acc += ctw[(t * 8 + j) * 512 + c * 64 + d * 8 + n] *
               attw[d * 512 + c * 64 + n * 8 + o];
    hb[M1_H + z] = (f16)acc;
  } else if (z < BF_H) {
    int z2 = z - BU_H;
    int j = z2 & 7, lane = (z2 >> 3) & 63, rest = z2 >> 9;
    int rs = rest % 12, c = rest / 12;
    int r = rs >> 2, s = rs & 3;
    int q = lane >> 4, l15 = lane & 15;
    int t = r * 4 + q;
    int d = 2 * s + (l15 >> 3), n = l15 & 7;
    float v = (t < 9) ? ctw[(t * 8 + j) * 512 + c * 64 + d * 8 + n] : 0.f;
    hb[z] = (f16)v;
  } else if (z < BC_H) {
    int z2 = z - BF_H;
    int j = z2 & 7, lane = (z2 >> 3) & 63, rest = z2 >> 9;
    int r = rest % 3, g = rest / 3;
    int q = lane >> 4, l15 = lane & 15;
    int t = r * 4 + q;
    int d = 2 * (j & 3) + (j >> 2);
    float v = 0.f;
    if (t < 9 && ((l15 >> 3) == (g & 1)))
      v = few[(t * 8 + d) * 64 + g * 8 + (l15 & 7)];
    hb[z] = (f16)v;
  } else if (z < VT_H) {
    int z2 = z - BC_H;
    int j = z2 & 7, lane = (z2 >> 3) & 63, rest = z2 >> 9;
    int s = rest & 3, c2 = rest >> 2;
    int q = lane >> 4, l15 = lane & 15;
    int nk = c2 * 4 + q;
    int nc = 2 * s + (l15 >> 3);
    float v = (nk == nc) ? caw[j * 64 + nc * 8 + (l15 & 7)] : 0.f;
    hb[z] = (f16)v;
  }
}

// Stage 1: logits GEMM -> softmax -> u GEMM + fold -> vt.
// R5: B-fragments staged to LDS via global_load_lds (T3-lite). 4 waves share
// one 12KB c-slice instead of each loading it from L2 (4x traffic cut, zero
// register cost -> no spill/collapse failure mode). Double-buffered bstage,
// distance-1: staging issued right after each barrier, cover = one c-step.
// One __syncthreads per step (implicit vmcnt(0) drain = pipeline wait).
// Everything else = R1-proven structure.
__global__ __launch_bounds__(256, 2) void caps_stage1(
    const float* __restrict__ in, const float* __restrict__ ws,
    const float* __restrict__ ctb, f16* __restrict__ vt) {
  __shared__ f16 xt[181 * 72];     // 26.1 KB, hp=180 = zero row
  __shared__ f16 attb[128 * 72];   // 18.4 KB; reused as vtmp in epilogue
  __shared__ f16 bstage[2][6144];  // 2 x 12 KB B-fragment slices
  int bid = blockIdx.x;
  int b = bid >> 5, t5 = bid & 31;
  int ty = t5 >> 3, tx = t5 & 7;
  int tid = threadIdx.x;
  int w = __builtin_amdgcn_readfirstlane(tid >> 6);
  int lane = tid & 63;
  int q = lane >> 4, l15 = lane & 15;
  int h = l15 >> 3, n = l15 & 7;

  const f16* hb = (const f16*)(ws + 64);
  const f16* m1h = hb + M1_H;
  const f16* buh = hb + BU_H;
  const float* lb = ws;

  // cooperative stage of one 12KB c-slice: wave w handles rows 3w..3w+2.
  // layout [rs][lane][8 f16] is contiguous in exactly lane order -> HW's
  // (uniform base + lane*16) rule matches with zero swizzle.
  auto stage = [&](const f16* src, int c, int bufi) {
    const f16* gs = src + c * 6144 + (w * 3) * 512 + lane * 8;
#pragma unroll
    for (int j = 0; j < 3; ++j)
      __builtin_amdgcn_global_load_lds(
          (gbl_void*)(gs + j * 512),
          (lds_void*)&bstage[bufi][(w * 3 + j) * 512], 16, 0, 0);
  };

  // prologue: stage M1 c=0,1 under the halo fill
  stage(m1h, 0, 0);
  stage(m1h, 1, 1);

  // fill halo tile (fp32 -> f16, transpose to ch = c*8+dd)
#pragma unroll
  for (int k = 0; k < 6; ++k) {
    int i = tid + k * 256;
    if (i < 181 * 8) {
      int c = i & 7, hp = i >> 3;
      float xs[8] = {0.f, 0.f, 0.f, 0.f, 0.f, 0.f, 0.f, 0.f};
      if (hp < 180) {
        int hy = hp / 10, hx = hp - hy * 10;
        int gy = ty * 16 + hy - 1, gx = tx * 8 + hx - 1;
        if (gy >= 0 && gy < HH && gx >= 0 && gx < WW) {
          const float* src = in + (((b * HH + gy) * WW + gx) * 64 + c);
#pragma unroll
          for (int d = 0; d < 8; ++d) xs[d] = src[d * 8];
        }
      }
      f16x8 pk;
#pragma unroll
      for (int d = 0; d < 8; ++d) pk[d] = (f16)xs[d];
      *(f16x8*)&xt[hp * 72 + c * 8] = pk;
    }
  }

  int hpt[2][3];
#pragma unroll
  for (int i2 = 0; i2 < 2; ++i2) {
    int pyA = (2 * w + i2) * 2 + h;
    int pxA = l15 & 7;
#pragma unroll
    for (int r = 0; r < 3; ++r) {
      int t = r * 4 + q;
      int hp = 180;
      if (t < 9) {
        int ky = t / 3, kx = t - ky * 3;
        hp = (pyA + ky) * 10 + pxA + kx;
      }
      hpt[i2][r] = hp * 72;
    }
  }

  f32x4 L[2][4];
#pragma unroll
  for (int s = 0; s < 4; ++s) {
    float v0 = lb[s * 16 + l15];
    L[0][s] = (f32x4){v0, v0, v0, v0};
    L[1][s] = (f32x4){v0, v0, v0, v0};
  }
  __syncthreads();  // halo ready + bstage c=0,1 landed (vmcnt drained)

  auto ldsB = [&](int bufi, f16x8(&bm)[12]) {
#pragma unroll
    for (int rs = 0; rs < 12; ++rs)
      bm[rs] = *(const f16x8*)&bstage[bufi][rs * 512 + lane * 8];
  };

  // ---- pass 1: logits GEMM, LDS-staged B ----
  auto p1step = [&](int c, int bufi) {
    f16x8 bm[12];
    ldsB(bufi, bm);
    f16x8 a[2][3];
#pragma unroll
    for (int i2 = 0; i2 < 2; ++i2)
#pragma unroll
      for (int r = 0; r < 3; ++r)
        a[i2][r] = *(const f16x8*)&xt[hpt[i2][r] + c * 8];
#pragma unroll
    for (int i2 = 0; i2 < 2; ++i2)
#pragma unroll
      for (int s = 0; s < 4; ++s)
#pragma unroll
        for (int r = 0; r < 3; ++r)
          L[i2][s] = __builtin_amdgcn_mfma_f32_16x16x32_f16(
              a[i2][r], bm[r * 4 + s], L[i2][s], 0, 0, 0);
  };

#pragma unroll 1
  for (int cc = 0; cc < 4; ++cc) {
    int c0 = 2 * cc;
    p1step(c0, 0);
    __syncthreads();  // all waves done with buf0; staged buf1 landed
    if (cc < 3) stage(m1h, c0 + 2, 0); else stage(buh, 0, 0);
    p1step(c0 + 1, 1);
    __syncthreads();  // all waves done with buf1; staged buf0 landed
    if (cc < 3) stage(m1h, c0 + 3, 1); else stage(buh, 1, 1);
  }

  // pass2 bias c=0,1: latency hides under softmax
  float cbA[4], cbB[4];
#pragma unroll
  for (int s = 0; s < 4; ++s) {
    cbA[s] = ctb[s * 16 + l15];
    cbB[s] = ctb[64 + s * 16 + l15];
  }

  // ---- softmax over o (4 in-lane s-frags + lane^8), att -> LDS ----
#pragma unroll
  for (int i2 = 0; i2 < 2; ++i2) {
    int pbase = (2 * w + i2) * 16 + q * 4;
#pragma unroll
    for (int r = 0; r < 4; ++r) {
      float v0 = L[i2][0][r], v1 = L[i2][1][r], v2 = L[i2][2][r], v3 = L[i2][3][r];
      float pm = fmaxf(fmaxf(v0, v1), fmaxf(v2, v3));
      float m = fmaxf(pm, __shfl_xor(pm, 8));
      float e0 = __expf(v0 - m), e1 = __expf(v1 - m);
      float e2 = __expf(v2 - m), e3 = __expf(v3 - m);
      float ps = e0 + e1 + e2 + e3;
      float inv = 1.f / (ps + __shfl_xor(ps, 8));
      int ab = (pbase + r) * 72 + n * 8 + h;  // o = 2s + h
      attb[ab + 0] = (f16)(e0 * inv);
      attb[ab + 2] = (f16)(e1 * inv);
      attb[ab + 4] = (f16)(e2 * inv);
      attb[ab + 6] = (f16)(e3 * inv);
    }
  }
  __syncthreads();  // attb ready + BU c=0,1 staging landed

  int ab[2][4];
#pragma unroll
  for (int i2 = 0; i2 < 2; ++i2)
#pragma unroll
    for (int r = 0; r < 4; ++r)
      ab[i2][r] = ((2 * w + i2) * 16 + q * 4 + r) * 72 + n * 8;

  // ---- pass 2: u GEMM + fold, LDS-staged B ----
  f32x4 V[2][4];
#pragma unroll
  for (int s = 0; s < 4; ++s) {
    V[0][s] = (f32x4){0.f, 0.f, 0.f, 0.f};
    V[1][s] = (f32x4){0.f, 0.f, 0.f, 0.f};
  }

  auto p2step = [&](int c, int bufi, const float(&cb)[4]) {
    f16x8 bm[12];
    ldsB(bufi, bm);
#pragma unroll
    for (int i2 = 0; i2 < 2; ++i2) {
      f16x8 a[3];
#pragma unroll
      for (int r = 0; r < 3; ++r)
        a[r] = *(const f16x8*)&xt[hpt[i2][r] + c * 8];
      f32x4 U[4];
#pragma unroll
      for (int s = 0; s < 4; ++s) U[s] = (f32x4){cb[s], cb[s], cb[s], cb[s]};
#pragma unroll
      for (int s = 0; s < 4; ++s)
#pragma unroll
        for (int r = 0; r < 3; ++r)
          U[s] = __builtin_amdgcn_mfma_f32_16x16x32_f16(
              a[r], bm[r * 4 + s], U[s], 0, 0, 0);
#pragma unroll
      for (int r = 0; r < 4; ++r) {
        float af = (float)attb[ab[i2][r] + c];
#pragma unroll
        for (int s = 0; s < 4; ++s) V[i2][s][r] += U[s][r] * af;
      }
    }
  };

#pragma unroll 1
  for (int cc = 0; cc < 4; ++cc) {
    int c0 = 2 * cc;
    p2step(c0, 0, cbA);
    __syncthreads();
    if (cc < 3) {
      stage(buh, c0 + 2, 0);
#pragma unroll
      for (int s = 0; s < 4; ++s) cbA[s] = ctb[(c0 + 2) * 64 + s * 16 + l15];
    }
    p2step(c0 + 1, 1, cbB);
    __syncthreads();
    if (cc < 3) {
      stage(buh, c0 + 3, 1);
#pragma unroll
      for (int s = 0; s < 4; ++s) cbB[s] = ctb[(c0 + 3) * 64 + s * 16 + l15];
    }
  }
  // loop ended with __syncthreads: all attb fold-reads complete

  // ---- epilogue: transpose V through attb (as vtmp), coalesced stores ----
  f16* vtmp = attb;
#pragma unroll
  for (int i2 = 0; i2 < 2; ++i2)
#pragma unroll
    for (int r = 0; r < 4; ++r) {
      int p = (2 * w + i2) * 16 + q * 4 + r;
      f16x4 st;
#pragma unroll
      for (int s = 0; s < 4; ++s) st[s] = (f16)V[i2][s][r];  // slot=h*4+s, d=2s+h
      *(f16x4*)&vtmp[p * 72 + n * 8 + h * 4] = st;
    }
  __syncthreads();
  for (int idx = tid; idx < 1024; idx += 256) {
    int p = idx >> 3, q2 = idx & 7;
    float4 val = *(float4*)&vtmp[p * 72 + q2 * 8];
    int gy = ty * 16 + (p >> 3), gx = tx * 8 + (p & 7);
    ((float4*)(vt + ((b * HH + gy) * WW + gx) * 64))[q2] = val;
  }
}

// Stage 2: FeaExt GEMM (block-diag, 1 s-frag per chunk) + ReLU + CapsAct GEMM -> out
// R5: R1 structure + bcf preload hidden under the fill barrier (proven in R3).
__global__ __launch_bounds__(256, 2) void caps_stage2(
    const f16* __restrict__ vt, const float* __restrict__ ws,
    const float* __restrict__ fb, const float* __restrict__ cab,
    float* __restrict__ out) {
  __shared__ float smemf[8704];  // 34.8 KB: vtile(26064B) / h1t(18432B) / outbuf aliased
  f16* vtile = (f16*)smemf;
  int bid = blockIdx.x;
  int b = bid >> 5, t5 = bid & 31;
  int ty = t5 >> 3, tx = t5 & 7;
  int tid = threadIdx.x;
  int w = __builtin_amdgcn_readfirstlane(tid >> 6);
  int lane = tid & 63;

  const f16x8* bfv = (const f16x8*)((const f16*)(ws + 64) + BF_H);
  const f16x8* bcv = (const f16x8*)((const f16*)(ws + 64) + BC_H);

  // preload CapsAct B-frags: latency hides under fill + FeaExt
  f16x8 bcf[8];
#pragma unroll
  for (int k = 0; k < 8; ++k) bcf[k] = bcv[k * 64 + lane];

  for (int i = tid; i < 181 * 8; i += 256) {
    int q2 = i & 7, hp = i >> 3;
    float4 val = make_float4(0.f, 0.f, 0.f, 0.f);
    if (hp < 180) {
      int hy = hp / 10, hx = hp - hy * 10;
      int gy = ty * 16 + hy - 1, gx = tx * 8 + hx - 1;
      if (gy >= 0 && gy < HH && gx >= 0 && gx < WW)
        val = ((const float4*)(vt + ((b * HH + gy) * WW + gx) * 64))[q2];
    }
    *(float4*)&vtile[hp * 72 + q2 * 8] = val;
  }
  __syncthreads();

  int q = lane >> 4, l15 = lane & 15;
  int h = l15 >> 3, j7 = l15 & 7;

  int hpt[2][3];
#pragma unroll
  for (int i2 = 0; i2 < 2; ++i2) {
    int pyA = (2 * w + i2) * 2 + h;
#pragma unroll
    for (int r = 0; r < 3; ++r) {
      int t = r * 4 + q;
      int hp = 180;
      if (t < 9) {
        int ky = t / 3, kx = t - ky * 3;
        hp = (pyA + ky) * 10 + j7 + kx;
      }
      hpt[i2][r] = hp * 72;
    }
  }

  // FeaExt: col (n=2s+h, j=j7); input chunk g feeds only s = g>>1
  f32x4 L[2][4];
#pragma unroll
  for (int s = 0; s < 4; ++s) {
    float bvv = fb[(2 * s + h) * 8 + j7];
    L[0][s] = (f32x4){bvv, bvv, bvv, bvv};
    L[1][s] = (f32x4){bvv, bvv, bvv, bvv};
  }
#pragma unroll
  for (int g = 0; g < 8; ++g) {
    int sg = g >> 1;
#pragma unroll
    for (int r = 0; r < 3; ++r) {
      f16x8 bf = bfv[(g * 3 + r) * 64 + lane];
#pragma unroll
      for (int i2 = 0; i2 < 2; ++i2) {
        f16x8 a = *(const f16x8*)&vtile[hpt[i2][r] + g * 8];
        L[i2][sg] = __builtin_amdgcn_mfma_f32_16x16x32_f16(a, bf, L[i2][sg], 0, 0, 0);
      }
    }
  }
#pragma unroll
  for (int i2 = 0; i2 < 2; ++i2)
#pragma unroll
    for (int s = 0; s < 4; ++s)
#pragma unroll
      for (int r = 0; r < 4; ++r) L[i2][s][r] = fmaxf(L[i2][s][r], 0.f);

  __syncthreads();  // vtile reads done; alias h1t
  f16* h1t = (f16*)smemf;  // [128][72], ch2 = n*8 + j1
#pragma unroll
  for (int i2 = 0; i2 < 2; ++i2)
#pragma unroll
    for (int s = 0; s < 4; ++s)
#pragma unroll
      for (int r = 0; r < 4; ++r)
        h1t[((2 * w + i2) * 16 + q * 4 + r) * 72 + (2 * s + h) * 8 + j7] =
            (f16)L[i2][s][r];
  __syncthreads();

  // CapsAct: K=64 over (j1, n) block-diag
  f32x4 H[2][4];
#pragma unroll
  for (int s = 0; s < 4; ++s) {
    float bvv = cab[(2 * s + h) * 8 + j7];
    H[0][s] = (f32x4){bvv, bvv, bvv, bvv};
    H[1][s] = (f32x4){bvv, bvv, bvv, bvv};
  }
#pragma unroll
  for (int c2 = 0; c2 < 2; ++c2) {
    f16x8 a2[2];
#pragma unroll
    for (int i2 = 0; i2 < 2; ++i2)
      a2[i2] = *(const f16x8*)&h1t[((2 * w + i2) * 16 + l15) * 72 + c2 * 32 + q * 8];
#pragma unroll
    for (int s = 0; s < 4; ++s) {
#pragma unroll
      for (int i2 = 0; i2 < 2; ++i2)
        H[i2][s] = __builtin_amdgcn_mfma_f32_16x16x32_f16(
            a2[i2], bcf[c2 * 4 + s], H[i2][s], 0, 0, 0);
    }
  }

  __syncthreads();  // h1t reads done; alias outbuf
  float* outbuf = smemf;  // [128][68], ch = j2*8 + n
#pragma unroll
  for (int i2 = 0; i2 < 2; ++i2)
#pragma unroll
    for (int s = 0; s < 4; ++s)
#pragma unroll
      for (int r = 0; r < 4; ++r)
        outbuf[((2 * w + i2) * 16 + q * 4 + r) * 68 + j7 * 8 + 2 * s + h] =
            H[i2][s][r];
  __syncthreads();

  for (int idx = tid; idx < 2048; idx += 256) {
    int p = idx >> 4, q4 = idx & 15;
    float4 val = *(float4*)&outbuf[p * 68 + q4 * 4];
    int gy = ty * 16 + (p >> 3), gx = tx * 8 + (p & 7);
    *(float4*)(out + ((b * HH + gy) * WW + gx) * 64 + q4 * 4) = val;
  }
}

extern "C" void kernel_launch(void* const* d_in, const int* in_sizes, int n_in,
                              void* d_out, int out_size, void* d_ws, size_t ws_size,
                              hipStream_t stream) {
  const float* inputs = (const float*)d_in[0];
  const float* attw   = (const float*)d_in[1];
  const float* ctw    = (const float*)d_in[2];
  const float* ctb    = (const float*)d_in[3];
  const float* few    = (const float*)d_in[4];
  const float* fb     = (const float*)d_in[5];
  const float* caw    = (const float*)d_in[6];
  const float* cab    = (const float*)d_in[7];
  float* out = (float*)d_out;
  float* ws  = (float*)d_ws;
  f16* vt = (f16*)(ws + 64) + VT_H;

  prep_kernel<<<(PREP_N + 255) / 256, 256, 0, stream>>>(attw, ctw, ctb, few, caw, ws);
  caps_stage1<<<32 * 32, 256, 0, stream>>>(inputs, ws, ctb, vt);
  caps_stage2<<<32 * 32, 256, 0, stream>>>(vt, ws, fb, cab, out);
}